// Round 1
// baseline (503.204 us; speedup 1.0000x reference)
//
#include <hip/hip_runtime.h>
#include <stdint.h>

typedef __attribute__((ext_vector_type(8))) __bf16 bf16x8;
typedef __attribute__((ext_vector_type(8))) unsigned short u16x8;
typedef __attribute__((ext_vector_type(4))) float f32x4;

#define MFMA16(a, b, c) __builtin_amdgcn_mfma_f32_16x16x32_bf16((a), (b), (c), 0, 0, 0)

static constexpr int NT = 4096;   // tokens
static constexpr int DM = 1024;   // model dim
static constexpr int NH = 16;     // heads
static constexpr int DH = 64;     // head dim
static constexpr int NB = 3072;   // qkv output cols

__device__ __forceinline__ unsigned short f2bf(float f) {
  union { float f; uint32_t u; } v; v.f = f;
  uint32_t u = v.u;
  return (unsigned short)((u + 0x7fffu + ((u >> 16) & 1u)) >> 16);
}
__device__ __forceinline__ float bf2f(unsigned short h) {
  union { uint32_t u; float f; } v; v.u = ((uint32_t)h) << 16;
  return v.f;
}
__device__ __forceinline__ void split_bf(float x, unsigned short& hi, unsigned short& lo) {
  hi = f2bf(x);
  lo = f2bf(x - bf2f(hi));
}

// ---------------- transpose + hi/lo split of fp32 weights ----------------
// src: [K][N] fp32 row-major -> dst: [N][K] bf16 (hi and optionally lo)
template <int SPLIT>
__global__ __launch_bounds__(256) void k_transpose_split(
    const float* __restrict__ src, int K, int N,
    unsigned short* __restrict__ dhi, unsigned short* __restrict__ dlo) {
  __shared__ float tile[64][65];
  const int tk = blockIdx.x * 64;
  const int tn = blockIdx.y * 64;
  const int t = threadIdx.x;
  const int rr = t >> 4, cc = (t & 15) * 4;
#pragma unroll
  for (int p = 0; p < 4; ++p) {
    int r = rr + p * 16;
    const float4 v = *reinterpret_cast<const float4*>(&src[(size_t)(tk + r) * N + tn + cc]);
    tile[r][cc] = v.x; tile[r][cc + 1] = v.y; tile[r][cc + 2] = v.z; tile[r][cc + 3] = v.w;
  }
  __syncthreads();
#pragma unroll
  for (int p = 0; p < 4; ++p) {
    int r = rr + p * 16;  // n offset
    size_t o = (size_t)(tn + r) * K + tk + cc;
    unsigned short hh[4], ll[4];
#pragma unroll
    for (int j = 0; j < 4; ++j) {
      float xv = tile[cc + j][r];
      split_bf(xv, hh[j], ll[j]);
    }
    *reinterpret_cast<ushort4*>(&dhi[o]) = make_ushort4(hh[0], hh[1], hh[2], hh[3]);
    if (SPLIT) *reinterpret_cast<ushort4*>(&dlo[o]) = make_ushort4(ll[0], ll[1], ll[2], ll[3]);
  }
}

// ---------------- RMSNorm (L2-normalize * sqrt(dim) * gamma) + split ----------------
__global__ __launch_bounds__(256) void k_rmsnorm_split(
    const float* __restrict__ x, const float* __restrict__ gamma,
    unsigned short* __restrict__ xh, unsigned short* __restrict__ xl) {
  const int row = blockIdx.x;
  const int t = threadIdx.x;  // 256 threads, 4 floats each
  const float4 v = reinterpret_cast<const float4*>(x + (size_t)row * DM)[t];
  float ss = v.x * v.x + v.y * v.y + v.z * v.z + v.w * v.w;
#pragma unroll
  for (int m = 1; m <= 32; m <<= 1) ss += __shfl_xor(ss, m);
  __shared__ float red[4];
  if ((t & 63) == 0) red[t >> 6] = ss;
  __syncthreads();
  float tot = red[0] + red[1] + red[2] + red[3];
  float inv = 32.0f * rsqrtf(fmaxf(tot, 1e-24f));  // sqrt(1024)=32; matches max(||x||,1e-12)
  const float4 g = reinterpret_cast<const float4*>(gamma)[t];
  float xs[4] = {v.x * inv * g.x, v.y * inv * g.y, v.z * inv * g.z, v.w * inv * g.w};
  unsigned short hh[4], ll[4];
#pragma unroll
  for (int j = 0; j < 4; ++j) split_bf(xs[j], hh[j], ll[j]);
  size_t o = (size_t)row * DM + t * 4;
  *reinterpret_cast<ushort4*>(&xh[o]) = make_ushort4(hh[0], hh[1], hh[2], hh[3]);
  *reinterpret_cast<ushort4*>(&xl[o]) = make_ushort4(ll[0], ll[1], ll[2], ll[3]);
}

// ---------------- QKV GEMM: [4096x1024] @ [1024x3072], split-bf16 (3 products) ----------------
// A = xn hi/lo [M][K]; B pre-transposed wqkvT hi/lo [N][K].
// epilogue scatters to q(hi/lo, *8), k(hi/lo), v per head layout [h][n][64].
__global__ __launch_bounds__(256) void k_qkv_gemm(
    const unsigned short* __restrict__ xh, const unsigned short* __restrict__ xl,
    const unsigned short* __restrict__ wh, const unsigned short* __restrict__ wl,
    unsigned short* __restrict__ qh, unsigned short* __restrict__ ql,
    unsigned short* __restrict__ kh, unsigned short* __restrict__ kl,
    unsigned short* __restrict__ vv) {
  __shared__ unsigned short sAh[128 * 40], sAl[128 * 40], sBh[128 * 40], sBl[128 * 40];
  const int t = threadIdx.x;
  const int l = t & 63, w = t >> 6;
  const int g = l >> 4, li = l & 15;
  const int m0 = blockIdx.y * 128, n0 = blockIdx.x * 128;
  const int wm = (w >> 1) * 64, wn = (w & 1) * 64;

  f32x4 acc[4][4];
#pragma unroll
  for (int a = 0; a < 4; ++a)
#pragma unroll
    for (int b = 0; b < 4; ++b) acc[a][b] = f32x4{0.f, 0.f, 0.f, 0.f};

  for (int k0 = 0; k0 < DM; k0 += 32) {
    __syncthreads();
#pragma unroll
    for (int i = 0; i < 2; ++i) {
      int c = t + i * 256;          // 512 16B-chunks per 128x32 tile
      int r = c >> 2, c8 = (c & 3) * 8;
      size_t ga = (size_t)(m0 + r) * DM + k0 + c8;
      size_t gb = (size_t)(n0 + r) * DM + k0 + c8;
      *(bf16x8*)&sAh[r * 40 + c8] = *(const bf16x8*)&xh[ga];
      *(bf16x8*)&sAl[r * 40 + c8] = *(const bf16x8*)&xl[ga];
      *(bf16x8*)&sBh[r * 40 + c8] = *(const bf16x8*)&wh[gb];
      *(bf16x8*)&sBl[r * 40 + c8] = *(const bf16x8*)&wl[gb];
    }
    __syncthreads();
    bf16x8 ah[4], al[4];
#pragma unroll
    for (int mt = 0; mt < 4; ++mt) {
      int off = (wm + mt * 16 + li) * 40 + g * 8;
      ah[mt] = *(const bf16x8*)&sAh[off];
      al[mt] = *(const bf16x8*)&sAl[off];
    }
#pragma unroll
    for (int nt = 0; nt < 4; ++nt) {
      int off = (wn + nt * 16 + li) * 40 + g * 8;
      bf16x8 bh = *(const bf16x8*)&sBh[off];
      bf16x8 bl = *(const bf16x8*)&sBl[off];
#pragma unroll
      for (int mt = 0; mt < 4; ++mt) {
        acc[mt][nt] = MFMA16(ah[mt], bh, acc[mt][nt]);
        acc[mt][nt] = MFMA16(ah[mt], bl, acc[mt][nt]);
        acc[mt][nt] = MFMA16(al[mt], bh, acc[mt][nt]);
      }
    }
  }
  // epilogue: C/D layout col=lane&15, row=4*(lane>>4)+reg  [verified m89]
#pragma unroll
  for (int mt = 0; mt < 4; ++mt)
#pragma unroll
    for (int nt = 0; nt < 4; ++nt)
#pragma unroll
      for (int r = 0; r < 4; ++r) {
        int row = m0 + wm + mt * 16 + 4 * g + r;
        int col = n0 + wn + nt * 16 + li;
        float val = acc[mt][nt][r];
        int which = col >> 10;          // uniform per block (128 | 1024)
        int head = (col >> 6) & 15;
        int d = col & 63;
        size_t o = ((size_t)head * NT + row) * DH + d;
        if (which == 0) {
          unsigned short hh, ll; split_bf(val * 8.0f, hh, ll);  // fold sqrt(dim_head)
          qh[o] = hh; ql[o] = ll;
        } else if (which == 1) {
          unsigned short hh, ll; split_bf(val, hh, ll);
          kh[o] = hh; kl[o] = ll;
        } else {
          vv[o] = f2bf(val);
        }
      }
}

// ---------------- causal flash attention ----------------
// grid (qtile=64 rows, head); 4 waves x 16 q-rows each; KV blocks of 64.
__global__ __launch_bounds__(256) void k_attn(
    const unsigned short* __restrict__ qh, const unsigned short* __restrict__ ql,
    const unsigned short* __restrict__ kh, const unsigned short* __restrict__ kl,
    const unsigned short* __restrict__ vv, unsigned short* __restrict__ oo) {
  __shared__ unsigned short sKh[64 * 72], sKl[64 * 72], sVt[64 * 72];  // padded rows
  __shared__ unsigned short sP[4][16 * 80];
  const int t = threadIdx.x;
  const int l = t & 63, w = t >> 6;
  const int g = l >> 4, li = l & 15;
  const int h = blockIdx.y;
  const int qt = blockIdx.x;
  const int q0 = qt * 64;

  // Q fragments in registers (A layout: m=lane&15, k=8*(lane>>4)+j), hi/lo
  size_t qoff = ((size_t)h * NT + q0 + w * 16 + li) * DH;
  bf16x8 qfh[2], qfl[2];
#pragma unroll
  for (int ks = 0; ks < 2; ++ks) {
    qfh[ks] = *(const bf16x8*)&qh[qoff + ks * 32 + g * 8];
    qfl[ks] = *(const bf16x8*)&ql[qoff + ks * 32 + g * 8];
  }

  f32x4 oacc[4];
#pragma unroll
  for (int dt = 0; dt < 4; ++dt) oacc[dt] = f32x4{0.f, 0.f, 0.f, 0.f};
  float mrun[4] = {-INFINITY, -INFINITY, -INFINITY, -INFINITY};
  float lsum[4] = {0.f, 0.f, 0.f, 0.f};

  for (int kb = 0; kb <= qt; ++kb) {
    const int kv0 = kb * 64;
    __syncthreads();  // previous iteration's LDS reads complete
#pragma unroll
    for (int i = 0; i < 2; ++i) {
      int c = t + i * 256;           // 512 chunks of 8 bf16 over 64x64
      int r = c >> 3, c8 = (c & 7) * 8;
      size_t go = ((size_t)h * NT + kv0 + r) * DH + c8;
      *(bf16x8*)&sKh[r * 72 + c8] = *(const bf16x8*)&kh[go];
      *(bf16x8*)&sKl[r * 72 + c8] = *(const bf16x8*)&kl[go];
      u16x8 vt = *(const u16x8*)&vv[go];
#pragma unroll
      for (int j = 0; j < 8; ++j) sVt[(c8 + j) * 72 + r] = vt[j];  // V transposed: [d][kv]
    }
    __syncthreads();

    // S = (8q)K^T via 3-product split bf16
    f32x4 s[4];
#pragma unroll
    for (int nt = 0; nt < 4; ++nt) s[nt] = f32x4{0.f, 0.f, 0.f, 0.f};
#pragma unroll
    for (int nt = 0; nt < 4; ++nt) {
#pragma unroll
      for (int ks = 0; ks < 2; ++ks) {
        int off = (nt * 16 + li) * 72 + ks * 32 + g * 8;
        bf16x8 bh = *(const bf16x8*)&sKh[off];
        bf16x8 bl = *(const bf16x8*)&sKl[off];
        s[nt] = MFMA16(qfh[ks], bh, s[nt]);
        s[nt] = MFMA16(qfh[ks], bl, s[nt]);
        s[nt] = MFMA16(qfl[ks], bh, s[nt]);
      }
    }
    if (kb == qt) {  // diagonal block: mask j > i
#pragma unroll
      for (int nt = 0; nt < 4; ++nt) {
        int j = kv0 + nt * 16 + li;
#pragma unroll
        for (int r = 0; r < 4; ++r) {
          int i2 = q0 + w * 16 + 4 * g + r;
          if (j > i2) s[nt][r] = -INFINITY;
        }
      }
    }
    // online softmax per output row (row = 4*g + r; reduce across 16 lanes of group)
#pragma unroll
    for (int r = 0; r < 4; ++r) {
      float rmax = fmaxf(fmaxf(s[0][r], s[1][r]), fmaxf(s[2][r], s[3][r]));
#pragma unroll
      for (int mm = 1; mm <= 8; mm <<= 1) rmax = fmaxf(rmax, __shfl_xor(rmax, mm));
      float mnew = fmaxf(mrun[r], rmax);
      float sc = __expf(mrun[r] - mnew);
      mrun[r] = mnew;
      float ps = 0.f;
#pragma unroll
      for (int nt = 0; nt < 4; ++nt) {
        float p = __expf(s[nt][r] - mnew);
        s[nt][r] = p;
        ps += p;
      }
#pragma unroll
      for (int mm = 1; mm <= 8; mm <<= 1) ps += __shfl_xor(ps, mm);
      lsum[r] = lsum[r] * sc + ps;
#pragma unroll
      for (int dt = 0; dt < 4; ++dt) oacc[dt][r] *= sc;
    }
    // P -> LDS (C/D layout) then read back in A layout; wave-private region
#pragma unroll
    for (int nt = 0; nt < 4; ++nt)
#pragma unroll
      for (int r = 0; r < 4; ++r)
        sP[w][(4 * g + r) * 80 + nt * 16 + li] = f2bf(s[nt][r]);
    // PV (plain bf16)
#pragma unroll
    for (int ks = 0; ks < 2; ++ks) {
      bf16x8 pa = *(const bf16x8*)&sP[w][li * 80 + ks * 32 + g * 8];
#pragma unroll
      for (int dt = 0; dt < 4; ++dt) {
        bf16x8 vb = *(const bf16x8*)&sVt[(dt * 16 + li) * 72 + ks * 32 + g * 8];
        oacc[dt] = MFMA16(pa, vb, oacc[dt]);
      }
    }
  }
  // epilogue: normalize and write [n][h*64+d] bf16
#pragma unroll
  for (int r = 0; r < 4; ++r) {
    float inv = 1.0f / lsum[r];
    int row = q0 + w * 16 + 4 * g + r;
#pragma unroll
    for (int dt = 0; dt < 4; ++dt) {
      int col = h * 64 + dt * 16 + li;
      oo[(size_t)row * DM + col] = f2bf(oacc[dt][r] * inv);
    }
  }
}

// ---------------- out projection: [4096x1024] @ [1024x1024], plain bf16 ----------------
__global__ __launch_bounds__(256) void k_out_gemm(
    const unsigned short* __restrict__ A, const unsigned short* __restrict__ Bt,
    float* __restrict__ C) {
  __shared__ unsigned short sA[128 * 40], sB[128 * 40];
  const int t = threadIdx.x;
  const int l = t & 63, w = t >> 6;
  const int g = l >> 4, li = l & 15;
  const int m0 = blockIdx.y * 128, n0 = blockIdx.x * 128;
  const int wm = (w >> 1) * 64, wn = (w & 1) * 64;

  f32x4 acc[4][4];
#pragma unroll
  for (int a = 0; a < 4; ++a)
#pragma unroll
    for (int b = 0; b < 4; ++b) acc[a][b] = f32x4{0.f, 0.f, 0.f, 0.f};

  for (int k0 = 0; k0 < DM; k0 += 32) {
    __syncthreads();
#pragma unroll
    for (int i = 0; i < 2; ++i) {
      int c = t + i * 256;
      int r = c >> 2, c8 = (c & 3) * 8;
      *(bf16x8*)&sA[r * 40 + c8] = *(const bf16x8*)&A[(size_t)(m0 + r) * DM + k0 + c8];
      *(bf16x8*)&sB[r * 40 + c8] = *(const bf16x8*)&Bt[(size_t)(n0 + r) * DM + k0 + c8];
    }
    __syncthreads();
    bf16x8 af[4];
#pragma unroll
    for (int mt = 0; mt < 4; ++mt)
      af[mt] = *(const bf16x8*)&sA[(wm + mt * 16 + li) * 40 + g * 8];
#pragma unroll
    for (int nt = 0; nt < 4; ++nt) {
      bf16x8 bfr = *(const bf16x8*)&sB[(wn + nt * 16 + li) * 40 + g * 8];
#pragma unroll
      for (int mt = 0; mt < 4; ++mt)
        acc[mt][nt] = MFMA16(af[mt], bfr, acc[mt][nt]);
    }
  }
#pragma unroll
  for (int mt = 0; mt < 4; ++mt)
#pragma unroll
    for (int nt = 0; nt < 4; ++nt)
#pragma unroll
      for (int r = 0; r < 4; ++r) {
        int row = m0 + wm + mt * 16 + 4 * g + r;
        int col = n0 + wn + nt * 16 + li;
        C[(size_t)row * DM + col] = acc[mt][nt][r];
      }
}

extern "C" void kernel_launch(void* const* d_in, const int* in_sizes, int n_in,
                              void* d_out, int out_size, void* d_ws, size_t ws_size,
                              hipStream_t stream) {
  const float* x     = (const float*)d_in[0];
  const float* gamma = (const float*)d_in[1];
  const float* wqkv  = (const float*)d_in[2];
  const float* wout  = (const float*)d_in[3];
  float* out = (float*)d_out;

  char* ws = (char*)d_ws;
  size_t off = 0;
  auto alloc = [&](size_t n) { char* p = ws + off; off += (n + 255) & ~(size_t)255; return p; };

  unsigned short* xh  = (unsigned short*)alloc((size_t)NT * DM * 2);
  unsigned short* xl  = (unsigned short*)alloc((size_t)NT * DM * 2);
  unsigned short* wqh = (unsigned short*)alloc((size_t)NB * DM * 2);
  unsigned short* wql = (unsigned short*)alloc((size_t)NB * DM * 2);
  unsigned short* qhp = (unsigned short*)alloc((size_t)NH * NT * DH * 2);
  unsigned short* qlp = (unsigned short*)alloc((size_t)NH * NT * DH * 2);
  unsigned short* khp = (unsigned short*)alloc((size_t)NH * NT * DH * 2);
  unsigned short* klp = (unsigned short*)alloc((size_t)NH * NT * DH * 2);
  unsigned short* vvp = (unsigned short*)alloc((size_t)NH * NT * DH * 2);
  unsigned short* ao  = (unsigned short*)alloc((size_t)NT * DM * 2);
  unsigned short* woT = (unsigned short*)alloc((size_t)DM * DM * 2);
  (void)ws_size; (void)in_sizes; (void)n_in; (void)out_size;

  k_transpose_split<1><<<dim3(DM / 64, NB / 64), 256, 0, stream>>>(wqkv, DM, NB, wqh, wql);
  k_transpose_split<0><<<dim3(DM / 64, DM / 64), 256, 0, stream>>>(wout, DM, DM, woT, nullptr);
  k_rmsnorm_split<<<NT, 256, 0, stream>>>(x, gamma, xh, xl);
  k_qkv_gemm<<<dim3(NB / 128, NT / 128), 256, 0, stream>>>(xh, xl, wqh, wql,
                                                           qhp, qlp, khp, klp, vvp);
  k_attn<<<dim3(NT / 64, NH), 256, 0, stream>>>(qhp, qlp, khp, klp, vvp, ao);
  k_out_gemm<<<dim3(DM / 128, NT / 128), 256, 0, stream>>>(ao, woT, out);
}

// Round 2
// 295.841 us; speedup vs baseline: 1.7009x; 1.7009x over previous
//
#include <hip/hip_runtime.h>
#include <stdint.h>

typedef __attribute__((ext_vector_type(8))) __bf16 bf16x8;
typedef __attribute__((ext_vector_type(4))) float f32x4;

#define MFMA16(a, b, c) __builtin_amdgcn_mfma_f32_16x16x32_bf16((a), (b), (c), 0, 0, 0)

static constexpr int NT = 4096;   // tokens
static constexpr int DM = 1024;   // model dim
static constexpr int NH = 16;     // heads
static constexpr int DH = 64;     // head dim
static constexpr int NB = 3072;   // qkv output cols

__device__ __forceinline__ unsigned short f2bf(float f) {
  union { float f; uint32_t u; } v; v.f = f;
  uint32_t u = v.u;
  return (unsigned short)((u + 0x7fffu + ((u >> 16) & 1u)) >> 16);
}
__device__ __forceinline__ float bf2f(unsigned short h) {
  union { uint32_t u; float f; } v; v.u = ((uint32_t)h) << 16;
  return v.f;
}
__device__ __forceinline__ void split_bf(float x, unsigned short& hi, unsigned short& lo) {
  hi = f2bf(x);
  lo = f2bf(x - bf2f(hi));
}

// ---------------- transpose + hi/lo split of fp32 weights ----------------
template <int SPLIT>
__global__ __launch_bounds__(256) void k_transpose_split(
    const float* __restrict__ src, int K, int N,
    unsigned short* __restrict__ dhi, unsigned short* __restrict__ dlo) {
  __shared__ float tile[64][65];
  const int tk = blockIdx.x * 64;
  const int tn = blockIdx.y * 64;
  const int t = threadIdx.x;
  const int rr = t >> 4, cc = (t & 15) * 4;
#pragma unroll
  for (int p = 0; p < 4; ++p) {
    int r = rr + p * 16;
    const float4 v = *reinterpret_cast<const float4*>(&src[(size_t)(tk + r) * N + tn + cc]);
    tile[r][cc] = v.x; tile[r][cc + 1] = v.y; tile[r][cc + 2] = v.z; tile[r][cc + 3] = v.w;
  }
  __syncthreads();
#pragma unroll
  for (int p = 0; p < 4; ++p) {
    int r = rr + p * 16;  // n offset
    size_t o = (size_t)(tn + r) * K + tk + cc;
    unsigned short hh[4], ll[4];
#pragma unroll
    for (int j = 0; j < 4; ++j) {
      float xv = tile[cc + j][r];
      split_bf(xv, hh[j], ll[j]);
    }
    *reinterpret_cast<ushort4*>(&dhi[o]) = make_ushort4(hh[0], hh[1], hh[2], hh[3]);
    if (SPLIT) *reinterpret_cast<ushort4*>(&dlo[o]) = make_ushort4(ll[0], ll[1], ll[2], ll[3]);
  }
}

// ---------------- RMSNorm (L2-normalize * sqrt(dim) * gamma) + split ----------------
__global__ __launch_bounds__(256) void k_rmsnorm_split(
    const float* __restrict__ x, const float* __restrict__ gamma,
    unsigned short* __restrict__ xh, unsigned short* __restrict__ xl) {
  const int row = blockIdx.x;
  const int t = threadIdx.x;
  const float4 v = reinterpret_cast<const float4*>(x + (size_t)row * DM)[t];
  float ss = v.x * v.x + v.y * v.y + v.z * v.z + v.w * v.w;
#pragma unroll
  for (int m = 1; m <= 32; m <<= 1) ss += __shfl_xor(ss, m);
  __shared__ float red[4];
  if ((t & 63) == 0) red[t >> 6] = ss;
  __syncthreads();
  float tot = red[0] + red[1] + red[2] + red[3];
  float inv = 32.0f * rsqrtf(fmaxf(tot, 1e-24f));
  const float4 g = reinterpret_cast<const float4*>(gamma)[t];
  float xs[4] = {v.x * inv * g.x, v.y * inv * g.y, v.z * inv * g.z, v.w * inv * g.w};
  unsigned short hh[4], ll[4];
#pragma unroll
  for (int j = 0; j < 4; ++j) split_bf(xs[j], hh[j], ll[j]);
  size_t o = (size_t)row * DM + t * 4;
  *reinterpret_cast<ushort4*>(&xh[o]) = make_ushort4(hh[0], hh[1], hh[2], hh[3]);
  *reinterpret_cast<ushort4*>(&xl[o]) = make_ushort4(ll[0], ll[1], ll[2], ll[3]);
}

// ---------------- QKV GEMM: split-bf16 (3 products); V written TRANSPOSED ----------------
__global__ __launch_bounds__(256) void k_qkv_gemm(
    const unsigned short* __restrict__ xh, const unsigned short* __restrict__ xl,
    const unsigned short* __restrict__ wh, const unsigned short* __restrict__ wl,
    unsigned short* __restrict__ qh, unsigned short* __restrict__ ql,
    unsigned short* __restrict__ kh, unsigned short* __restrict__ kl,
    unsigned short* __restrict__ vvT) {
  __shared__ unsigned short sAh[128 * 40], sAl[128 * 40], sBh[128 * 40], sBl[128 * 40];
  const int t = threadIdx.x;
  const int l = t & 63, w = t >> 6;
  const int g = l >> 4, li = l & 15;
  const int m0 = blockIdx.y * 128, n0 = blockIdx.x * 128;
  const int wm = (w >> 1) * 64, wn = (w & 1) * 64;

  f32x4 acc[4][4];
#pragma unroll
  for (int a = 0; a < 4; ++a)
#pragma unroll
    for (int b = 0; b < 4; ++b) acc[a][b] = f32x4{0.f, 0.f, 0.f, 0.f};

  for (int k0 = 0; k0 < DM; k0 += 32) {
    __syncthreads();
#pragma unroll
    for (int i = 0; i < 2; ++i) {
      int c = t + i * 256;
      int r = c >> 2, c8 = (c & 3) * 8;
      size_t ga = (size_t)(m0 + r) * DM + k0 + c8;
      size_t gb = (size_t)(n0 + r) * DM + k0 + c8;
      *(bf16x8*)&sAh[r * 40 + c8] = *(const bf16x8*)&xh[ga];
      *(bf16x8*)&sAl[r * 40 + c8] = *(const bf16x8*)&xl[ga];
      *(bf16x8*)&sBh[r * 40 + c8] = *(const bf16x8*)&wh[gb];
      *(bf16x8*)&sBl[r * 40 + c8] = *(const bf16x8*)&wl[gb];
    }
    __syncthreads();
    bf16x8 ah[4], al[4];
#pragma unroll
    for (int mt = 0; mt < 4; ++mt) {
      int off = (wm + mt * 16 + li) * 40 + g * 8;
      ah[mt] = *(const bf16x8*)&sAh[off];
      al[mt] = *(const bf16x8*)&sAl[off];
    }
#pragma unroll
    for (int nt = 0; nt < 4; ++nt) {
      int off = (wn + nt * 16 + li) * 40 + g * 8;
      bf16x8 bh = *(const bf16x8*)&sBh[off];
      bf16x8 bl = *(const bf16x8*)&sBl[off];
#pragma unroll
      for (int mt = 0; mt < 4; ++mt) {
        acc[mt][nt] = MFMA16(ah[mt], bh, acc[mt][nt]);
        acc[mt][nt] = MFMA16(ah[mt], bl, acc[mt][nt]);
        acc[mt][nt] = MFMA16(al[mt], bh, acc[mt][nt]);
      }
    }
  }
  // epilogue: C/D layout col=lane&15, row=4*(lane>>4)+reg
#pragma unroll
  for (int mt = 0; mt < 4; ++mt)
#pragma unroll
    for (int nt = 0; nt < 4; ++nt)
#pragma unroll
      for (int r = 0; r < 4; ++r) {
        int row = m0 + wm + mt * 16 + 4 * g + r;
        int col = n0 + wn + nt * 16 + li;
        float val = acc[mt][nt][r];
        int which = col >> 10;
        int head = (col >> 6) & 15;
        int d = col & 63;
        if (which == 0) {
          size_t o = ((size_t)head * NT + row) * DH + d;
          unsigned short hh, ll; split_bf(val * 8.0f, hh, ll);  // fold sqrt(dim_head)
          qh[o] = hh; ql[o] = ll;
        } else if (which == 1) {
          size_t o = ((size_t)head * NT + row) * DH + d;
          unsigned short hh, ll; split_bf(val, hh, ll);
          kh[o] = hh; kl[o] = ll;
        } else {
          // V stored transposed: [h][d][n]
          vvT[((size_t)head * DH + d) * NT + row] = f2bf(val);
        }
      }
}

// ---------------- causal flash attention ----------------
// 512 blocks: each handles q-tile pair (p, 63-p) for one head -> 65 KV-iters uniform.
// 4 waves x 16 q-rows; KV blocks of 64; async reg-staged K/V; V pre-transposed.
__global__ __launch_bounds__(256) void k_attn(
    const unsigned short* __restrict__ qh, const unsigned short* __restrict__ ql,
    const unsigned short* __restrict__ kh, const unsigned short* __restrict__ kl,
    const unsigned short* __restrict__ vvT, unsigned short* __restrict__ oo) {
  __shared__ unsigned short sKh[64 * 72], sKl[64 * 72], sVt[64 * 72];
  __shared__ unsigned short sP[4][16 * 72];
  const int t = threadIdx.x;
  const int l = t & 63, w = t >> 6;
  const int g = l >> 4, li = l & 15;
  const int bid = blockIdx.x;
  // XCD swizzle: 2 heads per XCD (K/V working set ~3MB < 4MB L2)
  const int h = (bid & 7) * 2 + ((bid >> 3) & 1);
  const int pair = bid >> 4;              // 0..31
  const int rs = t >> 3, cs = (t & 7) * 8;  // staging row/col for this thread

  for (int sel = 0; sel < 2; ++sel) {
    const int qt = sel ? (63 - pair) : pair;
    const int q0 = qt * 64;

    // Q fragments (A layout: m=lane&15, k=8*(lane>>4)+j), hi/lo
    size_t qoff = ((size_t)h * NT + q0 + w * 16 + li) * DH;
    bf16x8 qfh[2], qfl[2];
#pragma unroll
    for (int ks = 0; ks < 2; ++ks) {
      qfh[ks] = *(const bf16x8*)&qh[qoff + ks * 32 + g * 8];
      qfl[ks] = *(const bf16x8*)&ql[qoff + ks * 32 + g * 8];
    }

    f32x4 oacc[4];
#pragma unroll
    for (int dt = 0; dt < 4; ++dt) oacc[dt] = f32x4{0.f, 0.f, 0.f, 0.f};
    float mrun[4] = {-INFINITY, -INFINITY, -INFINITY, -INFINITY};
    float lsum[4] = {0.f, 0.f, 0.f, 0.f};

    bf16x8 rk[2], rl[2], rv[2];
    auto LOAD = [&](int kb) {
      const int kv0 = kb * 64;
#pragma unroll
      for (int i = 0; i < 2; ++i) {
        int r = rs + i * 32;
        size_t go = ((size_t)h * NT + kv0 + r) * DH + cs;
        rk[i] = *(const bf16x8*)&kh[go];
        rl[i] = *(const bf16x8*)&kl[go];
        rv[i] = *(const bf16x8*)&vvT[((size_t)h * DH + r) * NT + kv0 + cs];
      }
    };

    LOAD(0);
    for (int kb = 0; kb <= qt; ++kb) {
      const int kv0 = kb * 64;
      __syncthreads();  // previous iteration's LDS reads complete
#pragma unroll
      for (int i = 0; i < 2; ++i) {
        int r = rs + i * 32;
        *(bf16x8*)&sKh[r * 72 + cs] = rk[i];
        *(bf16x8*)&sKl[r * 72 + cs] = rl[i];
        *(bf16x8*)&sVt[r * 72 + cs] = rv[i];  // [d][kv]
      }
      __syncthreads();
      if (kb < qt) LOAD(kb + 1);  // overlap next-tile HBM latency with compute

      // S = (8q)K^T via 3-product split bf16
      f32x4 s[4];
#pragma unroll
      for (int nt = 0; nt < 4; ++nt) s[nt] = f32x4{0.f, 0.f, 0.f, 0.f};
#pragma unroll
      for (int nt = 0; nt < 4; ++nt) {
#pragma unroll
        for (int ks = 0; ks < 2; ++ks) {
          int off = (nt * 16 + li) * 72 + ks * 32 + g * 8;
          bf16x8 bh = *(const bf16x8*)&sKh[off];
          bf16x8 bl = *(const bf16x8*)&sKl[off];
          s[nt] = MFMA16(qfh[ks], bh, s[nt]);
          s[nt] = MFMA16(qfh[ks], bl, s[nt]);
          s[nt] = MFMA16(qfl[ks], bh, s[nt]);
        }
      }
      if (kb == qt) {  // diagonal block: mask j > i
#pragma unroll
        for (int nt = 0; nt < 4; ++nt) {
          int j = kv0 + nt * 16 + li;
#pragma unroll
          for (int r = 0; r < 4; ++r) {
            int i2 = q0 + w * 16 + 4 * g + r;
            if (j > i2) s[nt][r] = -INFINITY;
          }
        }
      }
      // online softmax per row (row = 4*g + r; reduce across 16 lanes)
#pragma unroll
      for (int r = 0; r < 4; ++r) {
        float rmax = fmaxf(fmaxf(s[0][r], s[1][r]), fmaxf(s[2][r], s[3][r]));
#pragma unroll
        for (int mm = 1; mm <= 8; mm <<= 1) rmax = fmaxf(rmax, __shfl_xor(rmax, mm));
        float mnew = fmaxf(mrun[r], rmax);
        float sc = __expf(mrun[r] - mnew);
        mrun[r] = mnew;
        float ps = 0.f;
#pragma unroll
        for (int nt = 0; nt < 4; ++nt) {
          float p = __expf(s[nt][r] - mnew);
          s[nt][r] = p;
          ps += p;
        }
#pragma unroll
        for (int mm = 1; mm <= 8; mm <<= 1) ps += __shfl_xor(ps, mm);
        lsum[r] = lsum[r] * sc + ps;
#pragma unroll
        for (int dt = 0; dt < 4; ++dt) oacc[dt][r] *= sc;
      }
      // P -> LDS (wave-private) then read back in A layout
#pragma unroll
      for (int nt = 0; nt < 4; ++nt)
#pragma unroll
        for (int r = 0; r < 4; ++r)
          sP[w][(4 * g + r) * 72 + nt * 16 + li] = f2bf(s[nt][r]);
      // PV (plain bf16)
#pragma unroll
      for (int ks = 0; ks < 2; ++ks) {
        bf16x8 pa = *(const bf16x8*)&sP[w][li * 72 + ks * 32 + g * 8];
#pragma unroll
        for (int dt = 0; dt < 4; ++dt) {
          bf16x8 vb = *(const bf16x8*)&sVt[(dt * 16 + li) * 72 + ks * 32 + g * 8];
          oacc[dt] = MFMA16(pa, vb, oacc[dt]);
        }
      }
    }
    // epilogue: normalize and write [n][h*64+d] bf16
#pragma unroll
    for (int r = 0; r < 4; ++r) {
      float inv = 1.0f / lsum[r];
      int row = q0 + w * 16 + 4 * g + r;
#pragma unroll
      for (int dt = 0; dt < 4; ++dt) {
        int col = h * 64 + dt * 16 + li;
        oo[(size_t)row * DM + col] = f2bf(oacc[dt][r] * inv);
      }
    }
  }
}

// ---------------- out projection: [4096x1024] @ [1024x1024], plain bf16 ----------------
__global__ __launch_bounds__(256) void k_out_gemm(
    const unsigned short* __restrict__ A, const unsigned short* __restrict__ Bt,
    float* __restrict__ C) {
  __shared__ unsigned short sA[128 * 40], sB[128 * 40];
  const int t = threadIdx.x;
  const int l = t & 63, w = t >> 6;
  const int g = l >> 4, li = l & 15;
  const int m0 = blockIdx.y * 128, n0 = blockIdx.x * 128;
  const int wm = (w >> 1) * 64, wn = (w & 1) * 64;

  f32x4 acc[4][4];
#pragma unroll
  for (int a = 0; a < 4; ++a)
#pragma unroll
    for (int b = 0; b < 4; ++b) acc[a][b] = f32x4{0.f, 0.f, 0.f, 0.f};

  for (int k0 = 0; k0 < DM; k0 += 32) {
    __syncthreads();
#pragma unroll
    for (int i = 0; i < 2; ++i) {
      int c = t + i * 256;
      int r = c >> 2, c8 = (c & 3) * 8;
      *(bf16x8*)&sA[r * 40 + c8] = *(const bf16x8*)&A[(size_t)(m0 + r) * DM + k0 + c8];
      *(bf16x8*)&sB[r * 40 + c8] = *(const bf16x8*)&Bt[(size_t)(n0 + r) * DM + k0 + c8];
    }
    __syncthreads();
    bf16x8 af[4];
#pragma unroll
    for (int mt = 0; mt < 4; ++mt)
      af[mt] = *(const bf16x8*)&sA[(wm + mt * 16 + li) * 40 + g * 8];
#pragma unroll
    for (int nt = 0; nt < 4; ++nt) {
      bf16x8 bfr = *(const bf16x8*)&sB[(wn + nt * 16 + li) * 40 + g * 8];
#pragma unroll
      for (int mt = 0; mt < 4; ++mt)
        acc[mt][nt] = MFMA16(af[mt], bfr, acc[mt][nt]);
    }
  }
#pragma unroll
  for (int mt = 0; mt < 4; ++mt)
#pragma unroll
    for (int nt = 0; nt < 4; ++nt)
#pragma unroll
      for (int r = 0; r < 4; ++r) {
        int row = m0 + wm + mt * 16 + 4 * g + r;
        int col = n0 + wn + nt * 16 + li;
        C[(size_t)row * DM + col] = acc[mt][nt][r];
      }
}

extern "C" void kernel_launch(void* const* d_in, const int* in_sizes, int n_in,
                              void* d_out, int out_size, void* d_ws, size_t ws_size,
                              hipStream_t stream) {
  const float* x     = (const float*)d_in[0];
  const float* gamma = (const float*)d_in[1];
  const float* wqkv  = (const float*)d_in[2];
  const float* wout  = (const float*)d_in[3];
  float* out = (float*)d_out;

  char* ws = (char*)d_ws;
  size_t off = 0;
  auto alloc = [&](size_t n) { char* p = ws + off; off += (n + 255) & ~(size_t)255; return p; };

  unsigned short* xh  = (unsigned short*)alloc((size_t)NT * DM * 2);
  unsigned short* xl  = (unsigned short*)alloc((size_t)NT * DM * 2);
  unsigned short* wqh = (unsigned short*)alloc((size_t)NB * DM * 2);
  unsigned short* wql = (unsigned short*)alloc((size_t)NB * DM * 2);
  unsigned short* qhp = (unsigned short*)alloc((size_t)NH * NT * DH * 2);
  unsigned short* qlp = (unsigned short*)alloc((size_t)NH * NT * DH * 2);
  unsigned short* khp = (unsigned short*)alloc((size_t)NH * NT * DH * 2);
  unsigned short* klp = (unsigned short*)alloc((size_t)NH * NT * DH * 2);
  unsigned short* vvT = (unsigned short*)alloc((size_t)NH * DH * NT * 2);
  unsigned short* ao  = (unsigned short*)alloc((size_t)NT * DM * 2);
  unsigned short* woT = (unsigned short*)alloc((size_t)DM * DM * 2);
  (void)ws_size; (void)in_sizes; (void)n_in; (void)out_size;

  k_transpose_split<1><<<dim3(DM / 64, NB / 64), 256, 0, stream>>>(wqkv, DM, NB, wqh, wql);
  k_transpose_split<0><<<dim3(DM / 64, DM / 64), 256, 0, stream>>>(wout, DM, DM, woT, nullptr);
  k_rmsnorm_split<<<NT, 256, 0, stream>>>(x, gamma, xh, xl);
  k_qkv_gemm<<<dim3(NB / 128, NT / 128), 256, 0, stream>>>(xh, xl, wqh, wql,
                                                           qhp, qlp, khp, klp, vvT);
  k_attn<<<512, 256, 0, stream>>>(qhp, qlp, khp, klp, vvT, ao);
  k_out_gemm<<<dim3(DM / 128, NT / 128), 256, 0, stream>>>(ao, woT, out);
}

// Round 3
// 282.855 us; speedup vs baseline: 1.7790x; 1.0459x over previous
//
#include <hip/hip_runtime.h>
#include <stdint.h>

typedef __attribute__((ext_vector_type(8))) __bf16 bf16x8;
typedef __attribute__((ext_vector_type(4))) float f32x4;

#define MFMA16(a, b, c) __builtin_amdgcn_mfma_f32_16x16x32_bf16((a), (b), (c), 0, 0, 0)

static constexpr int NT = 4096;   // tokens
static constexpr int DM = 1024;   // model dim
static constexpr int NH = 16;     // heads
static constexpr int DH = 64;     // head dim
static constexpr int NB = 3072;   // qkv output cols

__device__ __forceinline__ unsigned short f2bf(float f) {
  union { float f; uint32_t u; } v; v.f = f;
  uint32_t u = v.u;
  return (unsigned short)((u + 0x7fffu + ((u >> 16) & 1u)) >> 16);
}
__device__ __forceinline__ float bf2f(unsigned short h) {
  union { uint32_t u; float f; } v; v.u = ((uint32_t)h) << 16;
  return v.f;
}
__device__ __forceinline__ void split_bf(float x, unsigned short& hi, unsigned short& lo) {
  hi = f2bf(x);
  lo = f2bf(x - bf2f(hi));
}

// ---------------- transpose + hi/lo split of fp32 weights ----------------
template <int SPLIT>
__global__ __launch_bounds__(256) void k_transpose_split(
    const float* __restrict__ src, int K, int N,
    unsigned short* __restrict__ dhi, unsigned short* __restrict__ dlo) {
  __shared__ float tile[64][65];
  const int tk = blockIdx.x * 64;
  const int tn = blockIdx.y * 64;
  const int t = threadIdx.x;
  const int rr = t >> 4, cc = (t & 15) * 4;
#pragma unroll
  for (int p = 0; p < 4; ++p) {
    int r = rr + p * 16;
    const float4 v = *reinterpret_cast<const float4*>(&src[(size_t)(tk + r) * N + tn + cc]);
    tile[r][cc] = v.x; tile[r][cc + 1] = v.y; tile[r][cc + 2] = v.z; tile[r][cc + 3] = v.w;
  }
  __syncthreads();
#pragma unroll
  for (int p = 0; p < 4; ++p) {
    int r = rr + p * 16;  // n offset
    size_t o = (size_t)(tn + r) * K + tk + cc;
    unsigned short hh[4], ll[4];
#pragma unroll
    for (int j = 0; j < 4; ++j) {
      float xv = tile[cc + j][r];
      split_bf(xv, hh[j], ll[j]);
    }
    *reinterpret_cast<ushort4*>(&dhi[o]) = make_ushort4(hh[0], hh[1], hh[2], hh[3]);
    if (SPLIT) *reinterpret_cast<ushort4*>(&dlo[o]) = make_ushort4(ll[0], ll[1], ll[2], ll[3]);
  }
}

// ---------------- RMSNorm (L2-normalize * sqrt(dim) * gamma) + split ----------------
__global__ __launch_bounds__(256) void k_rmsnorm_split(
    const float* __restrict__ x, const float* __restrict__ gamma,
    unsigned short* __restrict__ xh, unsigned short* __restrict__ xl) {
  const int row = blockIdx.x;
  const int t = threadIdx.x;
  const float4 v = reinterpret_cast<const float4*>(x + (size_t)row * DM)[t];
  float ss = v.x * v.x + v.y * v.y + v.z * v.z + v.w * v.w;
#pragma unroll
  for (int m = 1; m <= 32; m <<= 1) ss += __shfl_xor(ss, m);
  __shared__ float red[4];
  if ((t & 63) == 0) red[t >> 6] = ss;
  __syncthreads();
  float tot = red[0] + red[1] + red[2] + red[3];
  float inv = 32.0f * rsqrtf(fmaxf(tot, 1e-24f));
  const float4 g = reinterpret_cast<const float4*>(gamma)[t];
  float xs[4] = {v.x * inv * g.x, v.y * inv * g.y, v.z * inv * g.z, v.w * inv * g.w};
  unsigned short hh[4], ll[4];
#pragma unroll
  for (int j = 0; j < 4; ++j) split_bf(xs[j], hh[j], ll[j]);
  size_t o = (size_t)row * DM + t * 4;
  *reinterpret_cast<ushort4*>(&xh[o]) = make_ushort4(hh[0], hh[1], hh[2], hh[3]);
  *reinterpret_cast<ushort4*>(&xl[o]) = make_ushort4(ll[0], ll[1], ll[2], ll[3]);
}

// ---------------- QKV GEMM: split-bf16; V cols plain bf16; V written TRANSPOSED ----------------
__global__ __launch_bounds__(256) void k_qkv_gemm(
    const unsigned short* __restrict__ xh, const unsigned short* __restrict__ xl,
    const unsigned short* __restrict__ wh, const unsigned short* __restrict__ wl,
    unsigned short* __restrict__ qh, unsigned short* __restrict__ ql,
    unsigned short* __restrict__ kh, unsigned short* __restrict__ kl,
    unsigned short* __restrict__ vvT) {
  __shared__ unsigned short sAh[128 * 40], sAl[128 * 40], sBh[128 * 40], sBl[128 * 40];
  const int t = threadIdx.x;
  const int l = t & 63, w = t >> 6;
  const int g = l >> 4, li = l & 15;
  const int m0 = blockIdx.y * 128, n0 = blockIdx.x * 128;
  const int wm = (w >> 1) * 64, wn = (w & 1) * 64;
  const bool vb = (n0 >= 2 * DM);  // V-column block: plain bf16 suffices

  f32x4 acc[4][4];
#pragma unroll
  for (int a = 0; a < 4; ++a)
#pragma unroll
    for (int b = 0; b < 4; ++b) acc[a][b] = f32x4{0.f, 0.f, 0.f, 0.f};

  for (int k0 = 0; k0 < DM; k0 += 32) {
    __syncthreads();
#pragma unroll
    for (int i = 0; i < 2; ++i) {
      int c = t + i * 256;
      int r = c >> 2, c8 = (c & 3) * 8;
      size_t ga = (size_t)(m0 + r) * DM + k0 + c8;
      size_t gb = (size_t)(n0 + r) * DM + k0 + c8;
      *(bf16x8*)&sAh[r * 40 + c8] = *(const bf16x8*)&xh[ga];
      *(bf16x8*)&sBh[r * 40 + c8] = *(const bf16x8*)&wh[gb];
      if (!vb) {
        *(bf16x8*)&sAl[r * 40 + c8] = *(const bf16x8*)&xl[ga];
        *(bf16x8*)&sBl[r * 40 + c8] = *(const bf16x8*)&wl[gb];
      }
    }
    __syncthreads();
    bf16x8 ah[4], al[4];
#pragma unroll
    for (int mt = 0; mt < 4; ++mt) {
      int off = (wm + mt * 16 + li) * 40 + g * 8;
      ah[mt] = *(const bf16x8*)&sAh[off];
      if (!vb) al[mt] = *(const bf16x8*)&sAl[off];
    }
#pragma unroll
    for (int nt = 0; nt < 4; ++nt) {
      int off = (wn + nt * 16 + li) * 40 + g * 8;
      bf16x8 bh = *(const bf16x8*)&sBh[off];
      if (vb) {
#pragma unroll
        for (int mt = 0; mt < 4; ++mt)
          acc[mt][nt] = MFMA16(ah[mt], bh, acc[mt][nt]);
      } else {
        bf16x8 bl = *(const bf16x8*)&sBl[off];
#pragma unroll
        for (int mt = 0; mt < 4; ++mt) {
          acc[mt][nt] = MFMA16(ah[mt], bh, acc[mt][nt]);
          acc[mt][nt] = MFMA16(ah[mt], bl, acc[mt][nt]);
          acc[mt][nt] = MFMA16(al[mt], bh, acc[mt][nt]);
        }
      }
    }
  }
  // epilogue: C/D layout col=lane&15, row=4*(lane>>4)+reg
#pragma unroll
  for (int mt = 0; mt < 4; ++mt)
#pragma unroll
    for (int nt = 0; nt < 4; ++nt)
#pragma unroll
      for (int r = 0; r < 4; ++r) {
        int row = m0 + wm + mt * 16 + 4 * g + r;
        int col = n0 + wn + nt * 16 + li;
        float val = acc[mt][nt][r];
        int which = col >> 10;
        int head = (col >> 6) & 15;
        int d = col & 63;
        if (which == 0) {
          size_t o = ((size_t)head * NT + row) * DH + d;
          // fold sqrt(dim_head)=8 AND log2(e) so softmax uses exp2
          unsigned short hh, ll; split_bf(val * 11.5415603f, hh, ll);
          qh[o] = hh; ql[o] = ll;
        } else if (which == 1) {
          size_t o = ((size_t)head * NT + row) * DH + d;
          unsigned short hh, ll; split_bf(val, hh, ll);
          kh[o] = hh; kl[o] = ll;
        } else {
          vvT[((size_t)head * DH + d) * NT + row] = f2bf(val);  // [h][d][n]
        }
      }
}

// ---------------- causal flash attention (swapped QK^T, O^T accum, KV-split) ------------
// 1024 blocks: (h, p, which). which=0: tile p full + tile 63-p KV-prefix (33 iters);
// which=1: tile 63-p KV-suffix (32 iters). Tiles qt>=32 merged by k_merge.
__global__ __launch_bounds__(256) void k_attn(
    const unsigned short* __restrict__ qh, const unsigned short* __restrict__ ql,
    const unsigned short* __restrict__ kh, const unsigned short* __restrict__ kl,
    const unsigned short* __restrict__ vvT, unsigned short* __restrict__ oo,
    float* __restrict__ part) {
  __shared__ unsigned short sKh[64 * 72], sKl[64 * 72], sVt[64 * 72];
  const int t = threadIdx.x;
  const int l = t & 63, w = t >> 6;
  const int g = l >> 4, li = l & 15;
  const int bid = blockIdx.x;
  const int h = (bid & 7) * 2 + ((bid >> 3) & 1);  // 2 heads per XCD
  const int rest = bid >> 4;                        // 0..63
  const int p = rest >> 1;                          // 0..31
  const int which = rest & 1;
  const int rs = t >> 3, cs = (t & 7) * 8;

  for (int si = 0; si < 2; ++si) {
    int qt, kb0, kb1, pslot;
    if (which == 0) {
      if (si == 0) { qt = p;      kb0 = 0;      kb1 = p;      pslot = -1; }
      else         { qt = 63 - p; kb0 = 0;      kb1 = 31 - p; pslot = (h * 32 + (31 - p)) * 2; }
    } else {
      if (si == 1) break;
      qt = 63 - p; kb0 = 32 - p; kb1 = 63 - p; pslot = (h * 32 + (31 - p)) * 2 + 1;
    }
    const int q0 = qt * 64;

    // Q fragments, standard packing (B operand of swapped QK): k = ks*32 + g*8 + j
    size_t qoff = ((size_t)h * NT + q0 + w * 16 + li) * DH;
    bf16x8 qfh[2], qfl[2];
#pragma unroll
    for (int ks = 0; ks < 2; ++ks) {
      qfh[ks] = *(const bf16x8*)&qh[qoff + ks * 32 + g * 8];
      qfl[ks] = *(const bf16x8*)&ql[qoff + ks * 32 + g * 8];
    }

    f32x4 oacc[4];  // O^T: lane holds O[q=li][d=16*mt+4*g+r]
#pragma unroll
    for (int mt = 0; mt < 4; ++mt) oacc[mt] = f32x4{0.f, 0.f, 0.f, 0.f};
    float mrun = -INFINITY, lsum = 0.f;

    bf16x8 rk[2], rl[2], rv[2];
    auto LOAD = [&](int kb) {
      const int kv0 = kb * 64;
#pragma unroll
      for (int i = 0; i < 2; ++i) {
        int r = rs + i * 32;
        size_t go = ((size_t)h * NT + kv0 + r) * DH + cs;
        rk[i] = *(const bf16x8*)&kh[go];
        rl[i] = *(const bf16x8*)&kl[go];
        rv[i] = *(const bf16x8*)&vvT[((size_t)h * DH + r) * NT + kv0 + cs];
      }
    };

    LOAD(kb0);
    for (int kb = kb0; kb <= kb1; ++kb) {
      const int kv0 = kb * 64;
      __syncthreads();
#pragma unroll
      for (int i = 0; i < 2; ++i) {
        int r = rs + i * 32;
        *(bf16x8*)&sKh[r * 72 + cs] = rk[i];
        *(bf16x8*)&sKl[r * 72 + cs] = rl[i];
        *(bf16x8*)&sVt[r * 72 + cs] = rv[i];
      }
      __syncthreads();
      if (kb < kb1) LOAD(kb + 1);

      // S^T = K * Q^T (3-product split): lane holds S[q=li][kv=16*mt+4*g+r]
      f32x4 s[4];
#pragma unroll
      for (int mt = 0; mt < 4; ++mt) s[mt] = f32x4{0.f, 0.f, 0.f, 0.f};
#pragma unroll
      for (int mt = 0; mt < 4; ++mt) {
#pragma unroll
        for (int ks = 0; ks < 2; ++ks) {
          int off = (mt * 16 + li) * 72 + ks * 32 + g * 8;
          bf16x8 ah = *(const bf16x8*)&sKh[off];
          bf16x8 al = *(const bf16x8*)&sKl[off];
          s[mt] = MFMA16(ah, qfh[ks], s[mt]);
          s[mt] = MFMA16(al, qfh[ks], s[mt]);
          s[mt] = MFMA16(ah, qfl[ks], s[mt]);
        }
      }
      if (kb == qt) {  // diagonal: mask kv > q
        int qg = q0 + w * 16 + li;
#pragma unroll
        for (int mt = 0; mt < 4; ++mt)
#pragma unroll
          for (int r = 0; r < 4; ++r)
            if (kv0 + mt * 16 + 4 * g + r > qg) s[mt][r] = -INFINITY;
      }
      // lane-local online softmax (log2 domain), row q=li spread over 4 g-lanes
      float vmax = -INFINITY;
#pragma unroll
      for (int mt = 0; mt < 4; ++mt)
#pragma unroll
        for (int r = 0; r < 4; ++r) vmax = fmaxf(vmax, s[mt][r]);
      vmax = fmaxf(vmax, __shfl_xor(vmax, 16));
      vmax = fmaxf(vmax, __shfl_xor(vmax, 32));
      float mnew = fmaxf(mrun, vmax);
      float sc = exp2f(mrun - mnew);
      float ps = 0.f;
#pragma unroll
      for (int mt = 0; mt < 4; ++mt)
#pragma unroll
        for (int r = 0; r < 4; ++r) {
          float pv = exp2f(s[mt][r] - mnew);
          s[mt][r] = pv;
          ps += pv;
        }
      ps += __shfl_xor(ps, 16);
      ps += __shfl_xor(ps, 32);
      lsum = lsum * sc + ps;
      mrun = mnew;
#pragma unroll
      for (int mt = 0; mt < 4; ++mt) oacc[mt] *= sc;

      // P fragments: pi-packing k = 32*ks + 16*(j>>2) + 4*g + (j&3) -> own registers
      union U8 { __bf16 e[8]; bf16x8 v; } pf[2];
#pragma unroll
      for (int ks = 0; ks < 2; ++ks)
#pragma unroll
        for (int j = 0; j < 8; ++j)
          pf[ks].e[j] = (__bf16)s[2 * ks + (j >> 2)][j & 3];

      // O^T += V^T * P^T  (A = V^T pi-packed from sVt, B = P)
#pragma unroll
      for (int mt = 0; mt < 4; ++mt) {
#pragma unroll
        for (int ks = 0; ks < 2; ++ks) {
          int ro = (mt * 16 + li) * 72 + ks * 32 + 4 * g;
          union U8 vf;
          *(ushort4*)&vf.e[0] = *(const ushort4*)&sVt[ro];
          *(ushort4*)&vf.e[4] = *(const ushort4*)&sVt[ro + 16];
          oacc[mt] = MFMA16(vf.v, pf[ks].v, oacc[mt]);
        }
      }
    }
    // epilogue
    if (pslot < 0) {
      float inv = 1.0f / lsum;
      int row = q0 + w * 16 + li;
#pragma unroll
      for (int mt = 0; mt < 4; ++mt) {
        ushort4 o4 = make_ushort4(f2bf(oacc[mt][0] * inv), f2bf(oacc[mt][1] * inv),
                                  f2bf(oacc[mt][2] * inv), f2bf(oacc[mt][3] * inv));
        *(ushort4*)&oo[(size_t)row * DM + h * 64 + mt * 16 + 4 * g] = o4;
      }
    } else {
      float* pb = part + (size_t)pslot * (64 * 64 + 128);
      int rq = w * 16 + li;
#pragma unroll
      for (int mt = 0; mt < 4; ++mt)
        *(f32x4*)&pb[rq * 64 + mt * 16 + 4 * g] = oacc[mt];
      if (g == 0) { pb[4096 + rq] = mrun; pb[4096 + 64 + rq] = lsum; }
    }
  }
}

// ---------------- merge two KV-split partials for tiles qt in [32,64) ----------------
__global__ __launch_bounds__(256) void k_merge(const float* __restrict__ part,
                                               unsigned short* __restrict__ oo) {
  const int b = blockIdx.x;  // h*32 + tb, tb = qt-32
  const int h = b >> 5, tb = b & 31;
  const float* p0 = part + (size_t)(b * 2) * (64 * 64 + 128);
  const float* p1 = p0 + (64 * 64 + 128);
  const int t = threadIdx.x;
  const int row = t >> 2, d0 = (t & 3) * 16;
  float m0 = p0[4096 + row], l0 = p0[4096 + 64 + row];
  float m1 = p1[4096 + row], l1 = p1[4096 + 64 + row];
  float mm = fmaxf(m0, m1);
  float w0 = exp2f(m0 - mm), w1 = exp2f(m1 - mm);
  float inv = 1.0f / (w0 * l0 + w1 * l1);
  const size_t grow = (size_t)((32 + tb) * 64 + row);
#pragma unroll
  for (int dd = 0; dd < 16; dd += 4) {
    f32x4 a = *(const f32x4*)&p0[row * 64 + d0 + dd];
    f32x4 c = *(const f32x4*)&p1[row * 64 + d0 + dd];
    ushort4 o4 = make_ushort4(f2bf((w0 * a[0] + w1 * c[0]) * inv),
                              f2bf((w0 * a[1] + w1 * c[1]) * inv),
                              f2bf((w0 * a[2] + w1 * c[2]) * inv),
                              f2bf((w0 * a[3] + w1 * c[3]) * inv));
    *(ushort4*)&oo[grow * DM + h * 64 + d0 + dd] = o4;
  }
}

// ---------------- out projection: [4096x1024] @ [1024x1024], plain bf16 ----------------
__global__ __launch_bounds__(256) void k_out_gemm(
    const unsigned short* __restrict__ A, const unsigned short* __restrict__ Bt,
    float* __restrict__ C) {
  __shared__ unsigned short sA[128 * 40], sB[128 * 40];
  const int t = threadIdx.x;
  const int l = t & 63, w = t >> 6;
  const int g = l >> 4, li = l & 15;
  const int m0 = blockIdx.y * 128, n0 = blockIdx.x * 128;
  const int wm = (w >> 1) * 64, wn = (w & 1) * 64;

  f32x4 acc[4][4];
#pragma unroll
  for (int a = 0; a < 4; ++a)
#pragma unroll
    for (int b = 0; b < 4; ++b) acc[a][b] = f32x4{0.f, 0.f, 0.f, 0.f};

  for (int k0 = 0; k0 < DM; k0 += 32) {
    __syncthreads();
#pragma unroll
    for (int i = 0; i < 2; ++i) {
      int c = t + i * 256;
      int r = c >> 2, c8 = (c & 3) * 8;
      *(bf16x8*)&sA[r * 40 + c8] = *(const bf16x8*)&A[(size_t)(m0 + r) * DM + k0 + c8];
      *(bf16x8*)&sB[r * 40 + c8] = *(const bf16x8*)&Bt[(size_t)(n0 + r) * DM + k0 + c8];
    }
    __syncthreads();
    bf16x8 af[4];
#pragma unroll
    for (int mt = 0; mt < 4; ++mt)
      af[mt] = *(const bf16x8*)&sA[(wm + mt * 16 + li) * 40 + g * 8];
#pragma unroll
    for (int nt = 0; nt < 4; ++nt) {
      bf16x8 bfr = *(const bf16x8*)&sB[(wn + nt * 16 + li) * 40 + g * 8];
#pragma unroll
      for (int mt = 0; mt < 4; ++mt)
        acc[mt][nt] = MFMA16(af[mt], bfr, acc[mt][nt]);
    }
  }
#pragma unroll
  for (int mt = 0; mt < 4; ++mt)
#pragma unroll
    for (int nt = 0; nt < 4; ++nt)
#pragma unroll
      for (int r = 0; r < 4; ++r) {
        int row = m0 + wm + mt * 16 + 4 * g + r;
        int col = n0 + wn + nt * 16 + li;
        C[(size_t)row * DM + col] = acc[mt][nt][r];
      }
}

extern "C" void kernel_launch(void* const* d_in, const int* in_sizes, int n_in,
                              void* d_out, int out_size, void* d_ws, size_t ws_size,
                              hipStream_t stream) {
  const float* x     = (const float*)d_in[0];
  const float* gamma = (const float*)d_in[1];
  const float* wqkv  = (const float*)d_in[2];
  const float* wout  = (const float*)d_in[3];
  float* out = (float*)d_out;

  char* ws = (char*)d_ws;
  size_t off = 0;
  auto alloc = [&](size_t n) { char* p = ws + off; off += (n + 255) & ~(size_t)255; return p; };

  unsigned short* xh  = (unsigned short*)alloc((size_t)NT * DM * 2);
  unsigned short* xl  = (unsigned short*)alloc((size_t)NT * DM * 2);
  unsigned short* wqh = (unsigned short*)alloc((size_t)NB * DM * 2);
  unsigned short* wql = (unsigned short*)alloc((size_t)NB * DM * 2);
  unsigned short* qhp = (unsigned short*)alloc((size_t)NH * NT * DH * 2);
  unsigned short* qlp = (unsigned short*)alloc((size_t)NH * NT * DH * 2);
  unsigned short* khp = (unsigned short*)alloc((size_t)NH * NT * DH * 2);
  unsigned short* klp = (unsigned short*)alloc((size_t)NH * NT * DH * 2);
  unsigned short* vvT = (unsigned short*)alloc((size_t)NH * DH * NT * 2);
  unsigned short* ao  = (unsigned short*)alloc((size_t)NT * DM * 2);
  unsigned short* woT = (unsigned short*)alloc((size_t)DM * DM * 2);
  float*          prt = (float*)alloc((size_t)1024 * (64 * 64 + 128) * 4);
  (void)ws_size; (void)in_sizes; (void)n_in; (void)out_size;

  k_transpose_split<1><<<dim3(DM / 64, NB / 64), 256, 0, stream>>>(wqkv, DM, NB, wqh, wql);
  k_transpose_split<0><<<dim3(DM / 64, DM / 64), 256, 0, stream>>>(wout, DM, DM, woT, nullptr);
  k_rmsnorm_split<<<NT, 256, 0, stream>>>(x, gamma, xh, xl);
  k_qkv_gemm<<<dim3(NB / 128, NT / 128), 256, 0, stream>>>(xh, xl, wqh, wql,
                                                           qhp, qlp, khp, klp, vvT);
  k_attn<<<1024, 256, 0, stream>>>(qhp, qlp, khp, klp, vvT, ao, prt);
  k_merge<<<512, 256, 0, stream>>>(prt, ao);
  k_out_gemm<<<dim3(DM / 128, NT / 128), 256, 0, stream>>>(ao, woT, out);
}